// Round 1
// baseline (594.309 us; speedup 1.0000x reference)
//
#include <hip/hip_runtime.h>

typedef __bf16 bf16;
typedef __bf16 bf16x8 __attribute__((ext_vector_type(8)));
typedef __bf16 bf16x4 __attribute__((ext_vector_type(4)));
typedef float  f32x4  __attribute__((ext_vector_type(4)));

#define BATCH   16
#define CDIM    512
#define NSPAT   4096
#define QKV_M   1536
#define INNER   512
#define GK      512   // K for both GEMMs
#define GNT     16    // GK/32 K-tiles

// async global->LDS, 16B per lane; LDS dest = wave-uniform base + lane*16
__device__ __forceinline__ void gld16(const bf16* g, const bf16* l) {
  __builtin_amdgcn_global_load_lds(
      (const __attribute__((address_space(1))) void*)g,
      (__attribute__((address_space(3))) void*)l, 16, 0, 0);
}

// raw barrier with compile-time memory fences (no vmcnt drain, unlike __syncthreads)
#define SBAR() do { asm volatile("" ::: "memory"); __builtin_amdgcn_s_barrier(); \
                    asm volatile("" ::: "memory"); } while (0)
#define LGKM0    asm volatile("s_waitcnt lgkmcnt(0)" ::: "memory")
#define VMCNT(n) asm volatile("s_waitcnt vmcnt(" #n ")" ::: "memory")

// ---------------------------------------------------------------------------
// f32 -> bf16 cast (weights)
// ---------------------------------------------------------------------------
__global__ __launch_bounds__(256) void cast_f32_bf16_kernel(
    const float* __restrict__ in, bf16* __restrict__ out, int n4) {
  int i = blockIdx.x * 256 + threadIdx.x;
  if (i >= n4) return;
  float4 v = ((const float4*)in)[i];
  bf16x4 o = { (bf16)v.x, (bf16)v.y, (bf16)v.z, (bf16)v.w };
  *(bf16x4*)(out + (size_t)i * 4) = o;
}

// ---------------------------------------------------------------------------
// x (B, C=512, N=4096) f32 -> xt (B, N, C) bf16   (64x64 LDS tile transpose)
// ---------------------------------------------------------------------------
__global__ __launch_bounds__(256) void transpose_cast_kernel(
    const float* __restrict__ x, bf16* __restrict__ xt) {
  __shared__ __attribute__((aligned(16))) bf16 T[64][72];
  int b = blockIdx.z, c0 = blockIdx.y * 64, n0 = blockIdx.x * 64;
  int t = threadIdx.x;
  const float* xp = x + ((size_t)b * CDIM + c0) * NSPAT + n0;
#pragma unroll
  for (int i = 0; i < 4; ++i) {
    int v = t + i * 256;
    int c = v >> 4, nq = (v & 15) * 4;
    float4 rd = *(const float4*)(xp + (size_t)c * NSPAT + nq);
    T[nq + 0][c] = (bf16)rd.x; T[nq + 1][c] = (bf16)rd.y;
    T[nq + 2][c] = (bf16)rd.z; T[nq + 3][c] = (bf16)rd.w;
  }
  __syncthreads();
  bf16* op = xt + ((size_t)b * NSPAT + n0) * CDIM + c0;
#pragma unroll
  for (int i = 0; i < 2; ++i) {
    int v = t + i * 256;
    int n = v >> 3, cc = (v & 7) * 8;
    *(bf16x8*)(op + (size_t)n * CDIM + cc) = *(const bf16x8*)&T[n][cc];
  }
}

// ---------------------------------------------------------------------------
// GEMM, 256x256 tile / 8-phase-style pipelined schedule (T3+T4+T2+T5):
//   C[b] = A(M,K) * Bt[b](N,K)^T, both k-contiguous, K=512 fixed.
//   512 thr = 8 waves (2m x 4n), per-wave 128x64 out, BK=32, 16 K-tiles.
//   LDS: 4-deep K-tile ring, 32 KiB/tile (A 16K ++ B 16K) = 128 KiB.
//   Staging: gld16 linear-dest; source pre-swizzled by involution
//   f(x)=x^((x>>3)&7) on 16B slots; ds_read uses the same swizzle ->
//   each 16-lane group covers all 8 bank-quads exactly twice (conflict-free).
//   vmcnt(8) once per K-tile: tiles t+2,t+3 stay in flight, never drain 0.
//   Race-free: tile t+3 staged during tile t; its slot held tile t-1, whose
//   reads completed before tile t-1's closing barrier.
// OUTMODE 0: bf16 C via per-wave LDS-transposed b128 stores.
// OUTMODE 1: f32 C + bias + per-batch LN partial sums (atomicAdd).
// ---------------------------------------------------------------------------
template <int OUTMODE>
__global__ __launch_bounds__(512, 2) void gemm256_kernel(
    const bf16* __restrict__ A, const bf16* __restrict__ Bt,
    void* __restrict__ Cout, const float* __restrict__ bias,
    float* __restrict__ part, int M, int N) {
  __shared__ __attribute__((aligned(16))) bf16 Sm[65536];  // 128 KiB

  int bz = blockIdx.z;
  int m0 = blockIdx.y * 256, n0 = blockIdx.x * 256;
  int tid = threadIdx.x, lane = tid & 63, wid = tid >> 6;
  int wm = wid >> 2, wn = wid & 3;          // 2 x 4 wave grid
  int lm = lane & 15, kqd = lane >> 4;

  // swizzled ds_read element-offsets (A-frags mf=0..7, B-frags nf=0..3)
  int aoff[8], boff[4];
#pragma unroll
  for (int mf = 0; mf < 8; ++mf) {
    int x = (mf * 16 + lm) * 4 + kqd;
    aoff[mf] = wm * 4096 + (x ^ ((x >> 3) & 7)) * 8;
  }
#pragma unroll
  for (int nf = 0; nf < 4; ++nf) {
    int x = ((wn & 1) * 64 + nf * 16 + lm) * 4 + kqd;
    boff[nf] = 8192 + (wn >> 1) * 4096 + (x ^ ((x >> 3) & 7)) * 8;
  }

  // staging: thread tid fills 16B slot #tid of each 128x32 half; pre-swizzled source
  int sl = tid ^ ((tid >> 3) & 7);
  int srow = sl >> 2, sc8 = (sl & 3) * 8;
  const bf16* aS = A + (size_t)(m0 + srow) * GK + sc8;
  const bf16* bS = Bt + ((size_t)bz * N + n0 + srow) * GK + sc8;

  f32x4 acc[8][4] = {};

#define STG_A(t) do { bf16* d = Sm + (((t)) & 3) * 16384 + wid * 512; \
    gld16(aS + (size_t)(t) * 32, d); \
    gld16(aS + (size_t)128 * GK + (size_t)(t) * 32, d + 4096); } while (0)
#define STG_B(t) do { bf16* d = Sm + (((t)) & 3) * 16384 + 8192 + wid * 512; \
    gld16(bS + (size_t)(t) * 32, d); \
    gld16(bS + (size_t)128 * GK + (size_t)(t) * 32, d + 4096); } while (0)

  // prologue: tiles 0,1,2 in flight; wait tile 0 (oldest 4 of 12 loads)
  STG_A(0); STG_B(0); STG_A(1); STG_B(1); STG_A(2); STG_B(2);
  VMCNT(8);
  SBAR();

#define TILE_BODY(t, DOSTG, WAITK) do { \
    const bf16* Sb = Sm + ((t) & 3) * 16384; \
    bf16x8 af[4], bq[4]; \
    _Pragma("unroll") for (int i = 0; i < 4; ++i) af[i] = *(const bf16x8*)(Sb + aoff[i]); \
    _Pragma("unroll") for (int i = 0; i < 4; ++i) bq[i] = *(const bf16x8*)(Sb + boff[i]); \
    if (DOSTG) STG_A((t) + 3); \
    SBAR(); LGKM0; \
    __builtin_amdgcn_s_setprio(1); \
    _Pragma("unroll") for (int i = 0; i < 4; ++i) \
      _Pragma("unroll") for (int j = 0; j < 4; ++j) \
        acc[i][j] = __builtin_amdgcn_mfma_f32_16x16x32_bf16(af[i], bq[j], acc[i][j], 0, 0, 0); \
    __builtin_amdgcn_s_setprio(0); \
    SBAR(); \
    _Pragma("unroll") for (int i = 0; i < 4; ++i) af[i] = *(const bf16x8*)(Sb + aoff[4 + i]); \
    if (DOSTG) STG_B((t) + 3); \
    SBAR(); LGKM0; \
    __builtin_amdgcn_s_setprio(1); \
    _Pragma("unroll") for (int i = 0; i < 4; ++i) \
      _Pragma("unroll") for (int j = 0; j < 4; ++j) \
        acc[4 + i][j] = __builtin_amdgcn_mfma_f32_16x16x32_bf16(af[i], bq[j], acc[4 + i][j], 0, 0, 0); \
    __builtin_amdgcn_s_setprio(0); \
    WAITK; \
    SBAR(); \
  } while (0)

  for (int tt = 0; tt < 12; tt += 4) {
#pragma unroll
    for (int q = 0; q < 4; ++q) TILE_BODY(tt + q, 1, VMCNT(8));
  }
  TILE_BODY(12, 1, VMCNT(8));   // stages tile 15
  TILE_BODY(13, 0, VMCNT(4));   // tile 14 landed, 15 in flight
  TILE_BODY(14, 0, VMCNT(0));   // tile 15 landed
  TILE_BODY(15, 0, (void)0);

  // C/D layout: col = n-base + lane&15, row = m-base + (lane>>4)*4 + r
  if (OUTMODE == 0) {
    bf16* C = (bf16*)Cout + (size_t)bz * M * N;
    bf16* Ws = Sm + wid * 8192;   // per-wave 128x64 staging (disjoint, no barriers)
#pragma unroll
    for (int mf = 0; mf < 8; ++mf)
#pragma unroll
      for (int nf = 0; nf < 4; ++nf)
#pragma unroll
        for (int r = 0; r < 4; ++r)
          Ws[(mf * 16 + kqd * 4 + r) * 64 + nf * 16 + lm] = (bf16)acc[mf][nf][r];
#pragma unroll
    for (int j = 0; j < 16; ++j) {
      int u = j * 64 + lane;
      int row = u >> 3, cu = (u & 7) * 8;
      *(bf16x8*)(C + (size_t)(m0 + wm * 128 + row) * N + (n0 + wn * 64 + cu)) =
          *(const bf16x8*)&Ws[row * 64 + cu];
    }
  } else {
    float* C = (float*)Cout + (size_t)bz * M * N;
    float s = 0.f, s2 = 0.f;
#pragma unroll
    for (int mf = 0; mf < 8; ++mf)
#pragma unroll
      for (int nf = 0; nf < 4; ++nf) {
        int row = m0 + wm * 128 + mf * 16 + kqd * 4;
        int col = n0 + wn * 64 + nf * 16 + lm;
#pragma unroll
        for (int r = 0; r < 4; ++r) {
          float v = acc[mf][nf][r] + bias[row + r];
          C[(size_t)(row + r) * N + col] = v;
          s += v; s2 += v * v;
        }
      }
#pragma unroll
    for (int off = 32; off > 0; off >>= 1) {
      s  += __shfl_down(s, off, 64);
      s2 += __shfl_down(s2, off, 64);
    }
    if (lane == 0) {
      atomicAdd(&part[bz * 2],     s);
      atomicAdd(&part[bz * 2 + 1], s2);
    }
  }
#undef TILE_BODY
#undef STG_A
#undef STG_B
}

// ---------------------------------------------------------------------------
// Attention scores, chunked: partial sc[bh][chunk][d][e] = sum_{n in chunk} q*k
// ---------------------------------------------------------------------------
__global__ __launch_bounds__(256) void attn_scores_kernel(
    const bf16* __restrict__ qkv, float* __restrict__ sc_part) {
  __shared__ __attribute__((aligned(16))) bf16 qs[4096];  // Qs[2048] ++ Ks[2048]
  int chunk = blockIdx.x, bh = blockIdx.y, b = bh >> 3, h = bh & 7;
  const bf16* q = qkv + ((size_t)b * QKV_M + h * 64) * NSPAT + chunk * 512;
  const bf16* k = q + (size_t)INNER * NSPAT;

  int tid = threadIdx.x, lane = tid & 63, wid = tid >> 6;
  int lm = lane & 15, kqd = lane >> 4, d0 = wid * 16;
  int srow = lane >> 2, skb = lane & 3;

  f32x4 acc[4] = {};
  for (int n0 = 0; n0 < 512; n0 += 32) {
    gld16(q + (size_t)(wid * 16 + srow) * NSPAT + n0 + skb * 8, qs + wid * 512);
    gld16(k + (size_t)(wid * 16 + srow) * NSPAT + n0 + skb * 8, qs + 2048 + wid * 512);
    __syncthreads();
    bf16x8 a = *(const bf16x8*)&qs[(d0 + lm) * 32 + kqd * 8];
#pragma unroll
    for (int eb = 0; eb < 4; ++eb) {
      bf16x8 bb = *(const bf16x8*)&qs[2048 + (eb * 16 + lm) * 32 + kqd * 8];
      acc[eb] = __builtin_amdgcn_mfma_f32_16x16x32_bf16(a, bb, acc[eb], 0, 0, 0);
    }
    __syncthreads();
  }
  float* outp = sc_part + ((size_t)bh * 8 + chunk) * 4096;
#pragma unroll
  for (int eb = 0; eb < 4; ++eb)
#pragma unroll
    for (int r = 0; r < 4; ++r)
      outp[(d0 + kqd * 4 + r) * 64 + eb * 16 + lm] = acc[eb][r];
}

// ---------------------------------------------------------------------------
// Softmax: sum 8 partial chunks, scale 1/8, softmax rows, bf16 attn weights
// ---------------------------------------------------------------------------
__global__ __launch_bounds__(256) void attn_softmax_kernel(
    const float* __restrict__ sc_part, bf16* __restrict__ attn_w) {
  __shared__ float ssum[64][65];
  int bh = blockIdx.x, t = threadIdx.x;
  const float* p = sc_part + (size_t)bh * 8 * 4096;
  float v[16];
#pragma unroll
  for (int j = 0; j < 16; ++j) v[j] = p[t + j * 256];
  for (int c = 1; c < 8; ++c)
#pragma unroll
    for (int j = 0; j < 16; ++j) v[j] += p[c * 4096 + t + j * 256];
#pragma unroll
  for (int j = 0; j < 16; ++j) {
    int q = t + j * 256;
    ssum[q >> 6][q & 63] = v[j];
  }
  __syncthreads();
  if (t < 64) {
    float mx = -1e30f;
    for (int e = 0; e < 64; ++e) mx = fmaxf(mx, ssum[t][e]);
    float s = 0.f;
    for (int e = 0; e < 64; ++e) {
      float ex = __expf((ssum[t][e] - mx) * 0.125f);
      ssum[t][e] = ex; s += ex;
    }
    float inv = 1.0f / s;
    bf16* ow = attn_w + (size_t)bh * 4096 + t * 64;
    for (int e = 0; e < 64; ++e) ow[e] = (bf16)(ssum[t][e] * inv);
  }
}

// ---------------------------------------------------------------------------
// PV: out^T[b][n][c] = (attn * v)^T, chunked over n. grid (8, 128).
// ---------------------------------------------------------------------------
__global__ __launch_bounds__(256) void attn_pv_kernel(
    const bf16* __restrict__ qkv, const bf16* __restrict__ attn_w,
    bf16* __restrict__ attn_t) {
  __shared__ __attribute__((aligned(16))) bf16 aw[64 * 72];
  __shared__ __attribute__((aligned(16))) bf16 Vs[128 * 72];  // reused as O^T staging
  int chunk = blockIdx.x, bh = blockIdx.y, b = bh >> 3, h = bh & 7;
  const bf16* vmat = qkv + ((size_t)b * QKV_M + 2 * INNER + h * 64) * NSPAT + chunk * 512;
  bf16* outt = attn_t + ((size_t)b * NSPAT + chunk * 512) * INNER + h * 64;

  int tid = threadIdx.x, lane = tid & 63, wid = tid >> 6;
  int lm = lane & 15, kqd = lane >> 4, d0 = wid * 16;

#pragma unroll
  for (int i = 0; i < 2; ++i) {
    int v = tid + i * 256;
    *(bf16x8*)&aw[(v >> 3) * 72 + (v & 7) * 8] = *(const bf16x8*)(attn_w + (size_t)bh * 4096 + v * 8);
  }
  __syncthreads();
  bf16x8 a0 = *(const bf16x8*)&aw[(d0 + lm) * 72 + kqd * 8];
  bf16x8 a1 = *(const bf16x8*)&aw[(d0 + lm) * 72 + 32 + kqd * 8];

  for (int nc = 0; nc < 512; nc += 128) {
    __syncthreads();
#pragma unroll
    for (int i = 0; i < 4; ++i) {
      int v = i * 256 + tid;
      int e = v & 63, nn = (v >> 6) * 8;
      bf16x8 d = *(const bf16x8*)(vmat + (size_t)e * NSPAT + nc + nn);
#pragma unroll
      for (int j = 0; j < 8; ++j) Vs[(nn + j) * 72 + e] = d[j];
    }
    __syncthreads();
    f32x4 o[8];
#pragma unroll
    for (int nt = 0; nt < 8; ++nt) {
      bf16x8 b0 = *(const bf16x8*)&Vs[(nt * 16 + lm) * 72 + kqd * 8];
      bf16x8 b1 = *(const bf16x8*)&Vs[(nt * 16 + lm) * 72 + 32 + kqd * 8];
      o[nt] = (f32x4){0.f, 0.f, 0.f, 0.f};
      o[nt] = __builtin_amdgcn_mfma_f32_16x16x32_bf16(a0, b0, o[nt], 0, 0, 0);
      o[nt] = __builtin_amdgcn_mfma_f32_16x16x32_bf16(a1, b1, o[nt], 0, 0, 0);
    }
    __syncthreads();
#pragma unroll
    for (int nt = 0; nt < 8; ++nt) {
      bf16x4 ov = { (bf16)o[nt][0], (bf16)o[nt][1], (bf16)o[nt][2], (bf16)o[nt][3] };
      *(bf16x4*)&Vs[(nt * 16 + lm) * 72 + d0 + kqd * 4] = ov;
    }
    __syncthreads();
#pragma unroll
    for (int i = 0; i < 4; ++i) {
      int v = i * 256 + tid;
      int n = v >> 3, dc = (v & 7) * 8;
      *(bf16x8*)(outt + (size_t)(nc + n) * INNER + dc) = *(const bf16x8*)&Vs[n * 72 + dc];
    }
  }
}

// ---------------------------------------------------------------------------
// LN stats + apply
// ---------------------------------------------------------------------------
__global__ void ln_stats_kernel(const float* __restrict__ part, float2* __restrict__ stats) {
  int b = threadIdx.x;
  if (b < 16) {
    const float invn = 1.0f / 2097152.0f;
    float mean = part[b * 2] * invn;
    float var  = part[b * 2 + 1] * invn - mean * mean;
    stats[b] = make_float2(mean, rsqrtf(var + 1e-5f));
  }
}

__global__ __launch_bounds__(256) void ln_apply_kernel(
    float* __restrict__ out, const float2* __restrict__ stats,
    const float* __restrict__ gamma, const float* __restrict__ beta) {
  size_t i4 = (size_t)blockIdx.x * 256 + threadIdx.x;
  size_t e  = i4 * 4;
  int b = (int)(e >> 21);
  int c = (int)((e >> 12) & 511);
  float2 st = stats[b];
  float g  = gamma[c] * st.y;
  float bb = beta[c] - st.x * g;
  float4* p = (float4*)out;
  float4 v = p[i4];
  v.x = v.x * g + bb; v.y = v.y * g + bb; v.z = v.z * g + bb; v.w = v.w * g + bb;
  p[i4] = v;
}

// ---------------------------------------------------------------------------
extern "C" void kernel_launch(void* const* d_in, const int* in_sizes, int n_in,
                              void* d_out, int out_size, void* d_ws, size_t ws_size,
                              hipStream_t stream) {
  const float* x      = (const float*)d_in[0];
  const float* w_qkv  = (const float*)d_in[1];
  const float* w_out  = (const float*)d_in[2];
  const float* b_out  = (const float*)d_in[3];
  const float* gamma  = (const float*)d_in[4];
  const float* beta   = (const float*)d_in[5];
  float* out = (float*)d_out;

  char* ws = (char*)d_ws;
  bf16*   xt      = (bf16*)(ws);                    // 64 MiB (B, N, C) — freed after QKV gemm
  float*  sc_part = (float*)(ws);                   // 16 MiB overlay (after xt's last use)
  bf16*   attn_w  = (bf16*)(ws + 16777216);         //  1 MiB overlay
  bf16*   wqkvb   = (bf16*)(ws + 67108864);         // 1.5 MiB
  bf16*   woutb   = (bf16*)(ws + 68681728);         // 0.5 MiB
  bf16*   qkvb    = (bf16*)(ws + 69206016);         // 192 MiB (B, 1536, N)
  bf16*   attn_t  = (bf16*)(ws + 270532608);        //  64 MiB (B, N, C)
  float*  part    = (float*)(ws + 337641472);       // 32 f32
  float2* stats   = (float2*)(ws + 337641600);      // 16 float2

  hipMemsetAsync(part, 0, 128, stream);

  transpose_cast_kernel<<<dim3(64, 8, BATCH), 256, 0, stream>>>(x, xt);
  cast_f32_bf16_kernel<<<768, 256, 0, stream>>>(w_qkv, wqkvb, 196608);
  cast_f32_bf16_kernel<<<256, 256, 0, stream>>>(w_out, woutb, 65536);

  // QKV projection: (1536x512) x (512x4096)^T per batch -> qkvb bf16
  gemm256_kernel<0><<<dim3(16, 6, BATCH), 512, 0, stream>>>(
      wqkvb, xt, (void*)qkvb, nullptr, nullptr, QKV_M, NSPAT);

  // channel attention
  attn_scores_kernel<<<dim3(8, 128), 256, 0, stream>>>(qkvb, sc_part);
  attn_softmax_kernel<<<128, 256, 0, stream>>>(sc_part, attn_w);
  attn_pv_kernel<<<dim3(8, 128), 256, 0, stream>>>(qkvb, attn_w, attn_t);

  // output projection + bias + LN partials -> d_out f32
  gemm256_kernel<1><<<dim3(16, 2, BATCH), 512, 0, stream>>>(
      woutb, attn_t, (void*)out, b_out, part, INNER, NSPAT);

  ln_stats_kernel<<<1, 16, 0, stream>>>(part, stats);
  ln_apply_kernel<<<32768, 256, 0, stream>>>(out, stats, gamma, beta);
}

// Round 2
// 562.596 us; speedup vs baseline: 1.0564x; 1.0564x over previous
//
#include <hip/hip_runtime.h>

typedef __bf16 bf16;
typedef __bf16 bf16x8 __attribute__((ext_vector_type(8)));
typedef __bf16 bf16x4 __attribute__((ext_vector_type(4)));
typedef float  f32x4  __attribute__((ext_vector_type(4)));

#define BATCH   16
#define CDIM    512
#define NSPAT   4096
#define QKV_M   1536
#define INNER   512
#define GK      512   // K for both GEMMs

// async global->LDS, 16B per lane; LDS dest = wave-uniform base + lane*16
__device__ __forceinline__ void gld16(const bf16* g, const bf16* l) {
  __builtin_amdgcn_global_load_lds(
      (const __attribute__((address_space(1))) void*)g,
      (__attribute__((address_space(3))) void*)l, 16, 0, 0);
}

// raw barrier with compile-time memory fences (no vmcnt drain, unlike __syncthreads)
#define SBAR() do { asm volatile("" ::: "memory"); __builtin_amdgcn_s_barrier(); \
                    asm volatile("" ::: "memory"); } while (0)
#define LGKM0    asm volatile("s_waitcnt lgkmcnt(0)" ::: "memory")
#define VMCNT(n) asm volatile("s_waitcnt vmcnt(" #n ")" ::: "memory")

// ---------------------------------------------------------------------------
// f32 -> bf16 cast (weights)
// ---------------------------------------------------------------------------
__global__ __launch_bounds__(256) void cast_f32_bf16_kernel(
    const float* __restrict__ in, bf16* __restrict__ out, int n4) {
  int i = blockIdx.x * 256 + threadIdx.x;
  if (i >= n4) return;
  float4 v = ((const float4*)in)[i];
  bf16x4 o = { (bf16)v.x, (bf16)v.y, (bf16)v.z, (bf16)v.w };
  *(bf16x4*)(out + (size_t)i * 4) = o;
}

// ---------------------------------------------------------------------------
// x (B, C=512, N=4096) f32 -> xt (B, N, C) bf16   (64x64 LDS tile transpose)
// ---------------------------------------------------------------------------
__global__ __launch_bounds__(256) void transpose_cast_kernel(
    const float* __restrict__ x, bf16* __restrict__ xt) {
  __shared__ __attribute__((aligned(16))) bf16 T[64][72];
  int b = blockIdx.z, c0 = blockIdx.y * 64, n0 = blockIdx.x * 64;
  int t = threadIdx.x;
  const float* xp = x + ((size_t)b * CDIM + c0) * NSPAT + n0;
#pragma unroll
  for (int i = 0; i < 4; ++i) {
    int v = t + i * 256;
    int c = v >> 4, nq = (v & 15) * 4;
    float4 rd = *(const float4*)(xp + (size_t)c * NSPAT + nq);
    T[nq + 0][c] = (bf16)rd.x; T[nq + 1][c] = (bf16)rd.y;
    T[nq + 2][c] = (bf16)rd.z; T[nq + 3][c] = (bf16)rd.w;
  }
  __syncthreads();
  bf16* op = xt + ((size_t)b * NSPAT + n0) * CDIM + c0;
#pragma unroll
  for (int i = 0; i < 2; ++i) {
    int v = t + i * 256;
    int n = v >> 3, cc = (v & 7) * 8;
    *(bf16x8*)(op + (size_t)n * CDIM + cc) = *(const bf16x8*)&T[n][cc];
  }
}

// ---------------------------------------------------------------------------
// GEMM, 256x256 tile / pipelined ring schedule (T2+T3+T4+T5) — used for QKV.
//   C[b] = A(M,K) * Bt[b](N,K)^T, both k-contiguous, K=512 fixed.
//   512 thr = 8 waves (2m x 4n), per-wave 128x64 out, BK=32, 16 K-tiles.
//   LDS: 4-deep K-tile ring, 32 KiB/tile (A 16K ++ B 16K) = 128 KiB.
//   Swizzle f(x)=x^((x>>3)&7) on 16B slots (both-sides: pre-swizzled global
//   source + swizzled ds_read). vmcnt(8) once per K-tile, never drained.
//   Measured r1: QKV 165 -> ~101 us, bank conflicts 0. Requires a B operand
//   that is cache-settled (clean lines); freshly-dirty B (attn_t) stalls the
//   2-wave/SIMD schedule -> do NOT use for the out-projection.
// ---------------------------------------------------------------------------
template <int OUTMODE>
__global__ __launch_bounds__(512, 2) void gemm256_kernel(
    const bf16* __restrict__ A, const bf16* __restrict__ Bt,
    void* __restrict__ Cout, const float* __restrict__ bias,
    float* __restrict__ part, int M, int N) {
  __shared__ __attribute__((aligned(16))) bf16 Sm[65536];  // 128 KiB

  int bz = blockIdx.z;
  int m0 = blockIdx.y * 256, n0 = blockIdx.x * 256;
  int tid = threadIdx.x, lane = tid & 63, wid = tid >> 6;
  int wm = wid >> 2, wn = wid & 3;          // 2 x 4 wave grid
  int lm = lane & 15, kqd = lane >> 4;

  // swizzled ds_read element-offsets (A-frags mf=0..7, B-frags nf=0..3)
  int aoff[8], boff[4];
#pragma unroll
  for (int mf = 0; mf < 8; ++mf) {
    int x = (mf * 16 + lm) * 4 + kqd;
    aoff[mf] = wm * 4096 + (x ^ ((x >> 3) & 7)) * 8;
  }
#pragma unroll
  for (int nf = 0; nf < 4; ++nf) {
    int x = ((wn & 1) * 64 + nf * 16 + lm) * 4 + kqd;
    boff[nf] = 8192 + (wn >> 1) * 4096 + (x ^ ((x >> 3) & 7)) * 8;
  }

  // staging: thread tid fills 16B slot #tid of each 128x32 half; pre-swizzled source
  int sl = tid ^ ((tid >> 3) & 7);
  int srow = sl >> 2, sc8 = (sl & 3) * 8;
  const bf16* aS = A + (size_t)(m0 + srow) * GK + sc8;
  const bf16* bS = Bt + ((size_t)bz * N + n0 + srow) * GK + sc8;

  f32x4 acc[8][4] = {};

#define STG_A(t) do { bf16* d = Sm + (((t)) & 3) * 16384 + wid * 512; \
    gld16(aS + (size_t)(t) * 32, d); \
    gld16(aS + (size_t)128 * GK + (size_t)(t) * 32, d + 4096); } while (0)
#define STG_B(t) do { bf16* d = Sm + (((t)) & 3) * 16384 + 8192 + wid * 512; \
    gld16(bS + (size_t)(t) * 32, d); \
    gld16(bS + (size_t)128 * GK + (size_t)(t) * 32, d + 4096); } while (0)

  // prologue: tiles 0,1,2 in flight; wait tile 0 (oldest 4 of 12 loads)
  STG_A(0); STG_B(0); STG_A(1); STG_B(1); STG_A(2); STG_B(2);
  VMCNT(8);
  SBAR();

#define TILE_BODY(t, DOSTG, WAITK) do { \
    const bf16* Sb = Sm + ((t) & 3) * 16384; \
    bf16x8 af[4], bq[4]; \
    _Pragma("unroll") for (int i = 0; i < 4; ++i) af[i] = *(const bf16x8*)(Sb + aoff[i]); \
    _Pragma("unroll") for (int i = 0; i < 4; ++i) bq[i] = *(const bf16x8*)(Sb + boff[i]); \
    if (DOSTG) STG_A((t) + 3); \
    SBAR(); LGKM0; \
    __builtin_amdgcn_s_setprio(1); \
    _Pragma("unroll") for (int i = 0; i < 4; ++i) \
      _Pragma("unroll") for (int j = 0; j < 4; ++j) \
        acc[i][j] = __builtin_amdgcn_mfma_f32_16x16x32_bf16(af[i], bq[j], acc[i][j], 0, 0, 0); \
    __builtin_amdgcn_s_setprio(0); \
    SBAR(); \
    _Pragma("unroll") for (int i = 0; i < 4; ++i) af[i] = *(const bf16x8*)(Sb + aoff[4 + i]); \
    if (DOSTG) STG_B((t) + 3); \
    SBAR(); LGKM0; \
    __builtin_amdgcn_s_setprio(1); \
    _Pragma("unroll") for (int i = 0; i < 4; ++i) \
      _Pragma("unroll") for (int j = 0; j < 4; ++j) \
        acc[4 + i][j] = __builtin_amdgcn_mfma_f32_16x16x32_bf16(af[i], bq[j], acc[4 + i][j], 0, 0, 0); \
    __builtin_amdgcn_s_setprio(0); \
    WAITK; \
    SBAR(); \
  } while (0)

  for (int tt = 0; tt < 12; tt += 4) {
#pragma unroll
    for (int q = 0; q < 4; ++q) TILE_BODY(tt + q, 1, VMCNT(8));
  }
  TILE_BODY(12, 1, VMCNT(8));   // stages tile 15
  TILE_BODY(13, 0, VMCNT(4));   // tile 14 landed, 15 in flight
  TILE_BODY(14, 0, VMCNT(0));   // tile 15 landed
  TILE_BODY(15, 0, (void)0);

  // C/D layout: col = n-base + lane&15, row = m-base + (lane>>4)*4 + r
  if (OUTMODE == 0) {
    bf16* C = (bf16*)Cout + (size_t)bz * M * N;
    bf16* Ws = Sm + wid * 8192;   // per-wave 128x64 staging (disjoint, no barriers)
#pragma unroll
    for (int mf = 0; mf < 8; ++mf)
#pragma unroll
      for (int nf = 0; nf < 4; ++nf)
#pragma unroll
        for (int r = 0; r < 4; ++r)
          Ws[(mf * 16 + kqd * 4 + r) * 64 + nf * 16 + lm] = (bf16)acc[mf][nf][r];
#pragma unroll
    for (int j = 0; j < 16; ++j) {
      int u = j * 64 + lane;
      int row = u >> 3, cu = (u & 7) * 8;
      *(bf16x8*)(C + (size_t)(m0 + wm * 128 + row) * N + (n0 + wn * 64 + cu)) =
          *(const bf16x8*)&Ws[row * 64 + cu];
    }
  } else {
    float* C = (float*)Cout + (size_t)bz * M * N;
    float s = 0.f, s2 = 0.f;
#pragma unroll
    for (int mf = 0; mf < 8; ++mf)
#pragma unroll
      for (int nf = 0; nf < 4; ++nf) {
        int row = m0 + wm * 128 + mf * 16 + kqd * 4;
        int col = n0 + wn * 64 + nf * 16 + lm;
#pragma unroll
        for (int r = 0; r < 4; ++r) {
          float v = acc[mf][nf][r] + bias[row + r];
          C[(size_t)(row + r) * N + col] = v;
          s += v; s2 += v * v;
        }
      }
#pragma unroll
    for (int off = 32; off > 0; off >>= 1) {
      s  += __shfl_down(s, off, 64);
      s2 += __shfl_down(s2, off, 64);
    }
    if (lane == 0) {
      atomicAdd(&part[bz * 2],     s);
      atomicAdd(&part[bz * 2 + 1], s2);
    }
  }
#undef TILE_BODY
#undef STG_A
#undef STG_B
}

// ---------------------------------------------------------------------------
// GEMM (m97 structure, round-0 known-good): used for the out-projection.
// 128x128 tile, BK=32, global_load_lds staging, 4 waves x (4x4) 16x16x32 MFMA.
// __syncthreads-drain schedule, 16 KiB LDS -> ~3 blocks/CU: latency-tolerant
// to the freshly-dirty attn_t B-operand (the 256^2 ring kernel is not).
// OUTMODE 1: f32 C + bias + per-batch LN partial sums (atomicAdd).
// ---------------------------------------------------------------------------
template <int OUTMODE>
__global__ __launch_bounds__(256) void gemm_tn_kernel(
    const bf16* __restrict__ A, const bf16* __restrict__ Bt,
    void* __restrict__ Cout, const float* __restrict__ bias,
    float* __restrict__ part, int M, int N, int K) {
  __shared__ __attribute__((aligned(16))) bf16 smem[8192];  // As[4096] ++ Bs[4096]

  int b  = blockIdx.z;
  int m0 = blockIdx.y * 128, n0 = blockIdx.x * 128;
  const bf16* Ab = A + (size_t)m0 * K;
  const bf16* Bb = Bt + ((size_t)b * N + n0) * K;

  int tid = threadIdx.x, lane = tid & 63, wid = tid >> 6;
  int wm = wid >> 1, wn = wid & 1, lm = lane & 15, kqd = lane >> 4;
  int srow = lane >> 2, skb = lane & 3;

  f32x4 acc[4][4] = {};

  for (int k0 = 0; k0 < K; k0 += 32) {
#pragma unroll
    for (int i = 0; i < 2; ++i) {
      int gi = wid * 2 + i;
      gld16(Ab + (size_t)(gi * 16 + srow) * K + k0 + skb * 8, smem + gi * 512);
      gld16(Bb + (size_t)(gi * 16 + srow) * K + k0 + skb * 8, smem + 4096 + gi * 512);
    }
    __syncthreads();
    bf16x8 af[4], bfr[4];
#pragma unroll
    for (int im = 0; im < 4; ++im)
      af[im] = *(const bf16x8*)&smem[(wm * 64 + im * 16 + lm) * 32 + kqd * 8];
#pragma unroll
    for (int in = 0; in < 4; ++in)
      bfr[in] = *(const bf16x8*)&smem[4096 + (wn * 64 + in * 16 + lm) * 32 + kqd * 8];
#pragma unroll
    for (int im = 0; im < 4; ++im)
#pragma unroll
      for (int in = 0; in < 4; ++in)
        acc[im][in] = __builtin_amdgcn_mfma_f32_16x16x32_bf16(af[im], bfr[in], acc[im][in], 0, 0, 0);
    __syncthreads();
  }

  // C/D layout: col = lane&15, row = (lane>>4)*4 + r
  if (OUTMODE == 0) {
    bf16* C = (bf16*)Cout + (size_t)b * M * N;
    bf16* Ws = smem + wid * 2048;   // per-wave 32x64 staging (no barriers needed)
#pragma unroll
    for (int half = 0; half < 2; ++half) {
#pragma unroll
      for (int im2 = 0; im2 < 2; ++im2) {
        int im = half * 2 + im2;
#pragma unroll
        for (int in = 0; in < 4; ++in)
#pragma unroll
          for (int r = 0; r < 4; ++r)
            Ws[(im2 * 16 + kqd * 4 + r) * 64 + in * 16 + lm] = (bf16)acc[im][in][r];
      }
#pragma unroll
      for (int j = 0; j < 4; ++j) {
        int u = lane + j * 64;
        int row = u >> 3, cu = (u & 7) * 8;
        *(bf16x8*)(C + (size_t)(m0 + wm * 64 + half * 32 + row) * N + n0 + wn * 64 + cu) =
            *(const bf16x8*)&Ws[row * 64 + cu];
      }
    }
  } else {
    float* C = (float*)Cout + (size_t)b * M * N;
    float s = 0.f, s2 = 0.f;
#pragma unroll
    for (int im = 0; im < 4; ++im)
#pragma unroll
      for (int in = 0; in < 4; ++in) {
        int row = m0 + wm * 64 + im * 16 + kqd * 4;
        int col = n0 + wn * 64 + in * 16 + lm;
#pragma unroll
        for (int r = 0; r < 4; ++r) {
          float v = acc[im][in][r] + bias[row + r];
          C[(size_t)(row + r) * N + col] = v;
          s += v; s2 += v * v;
        }
      }
#pragma unroll
    for (int off = 32; off > 0; off >>= 1) {
      s  += __shfl_down(s, off, 64);
      s2 += __shfl_down(s2, off, 64);
    }
    __shared__ float red[8];
    if (lane == 0) { red[wid] = s; red[wid + 4] = s2; }
    __syncthreads();
    if (tid == 0) {
      atomicAdd(&part[b * 2],     red[0] + red[1] + red[2] + red[3]);
      atomicAdd(&part[b * 2 + 1], red[4] + red[5] + red[6] + red[7]);
    }
  }
}

// ---------------------------------------------------------------------------
// Attention scores, chunked: partial sc[bh][chunk][d][e] = sum_{n in chunk} q*k
// ---------------------------------------------------------------------------
__global__ __launch_bounds__(256) void attn_scores_kernel(
    const bf16* __restrict__ qkv, float* __restrict__ sc_part) {
  __shared__ __attribute__((aligned(16))) bf16 qs[4096];  // Qs[2048] ++ Ks[2048]
  int chunk = blockIdx.x, bh = blockIdx.y, b = bh >> 3, h = bh & 7;
  const bf16* q = qkv + ((size_t)b * QKV_M + h * 64) * NSPAT + chunk * 512;
  const bf16* k = q + (size_t)INNER * NSPAT;

  int tid = threadIdx.x, lane = tid & 63, wid = tid >> 6;
  int lm = lane & 15, kqd = lane >> 4, d0 = wid * 16;
  int srow = lane >> 2, skb = lane & 3;

  f32x4 acc[4] = {};
  for (int n0 = 0; n0 < 512; n0 += 32) {
    gld16(q + (size_t)(wid * 16 + srow) * NSPAT + n0 + skb * 8, qs + wid * 512);
    gld16(k + (size_t)(wid * 16 + srow) * NSPAT + n0 + skb * 8, qs + 2048 + wid * 512);
    __syncthreads();
    bf16x8 a = *(const bf16x8*)&qs[(d0 + lm) * 32 + kqd * 8];
#pragma unroll
    for (int eb = 0; eb < 4; ++eb) {
      bf16x8 bb = *(const bf16x8*)&qs[2048 + (eb * 16 + lm) * 32 + kqd * 8];
      acc[eb] = __builtin_amdgcn_mfma_f32_16x16x32_bf16(a, bb, acc[eb], 0, 0, 0);
    }
    __syncthreads();
  }
  float* outp = sc_part + ((size_t)bh * 8 + chunk) * 4096;
#pragma unroll
  for (int eb = 0; eb < 4; ++eb)
#pragma unroll
    for (int r = 0; r < 4; ++r)
      outp[(d0 + kqd * 4 + r) * 64 + eb * 16 + lm] = acc[eb][r];
}

// ---------------------------------------------------------------------------
// Softmax: sum 8 partial chunks, scale 1/8, softmax rows, bf16 attn weights
// ---------------------------------------------------------------------------
__global__ __launch_bounds__(256) void attn_softmax_kernel(
    const float* __restrict__ sc_part, bf16* __restrict__ attn_w) {
  __shared__ float ssum[64][65];
  int bh = blockIdx.x, t = threadIdx.x;
  const float* p = sc_part + (size_t)bh * 8 * 4096;
  float v[16];
#pragma unroll
  for (int j = 0; j < 16; ++j) v[j] = p[t + j * 256];
  for (int c = 1; c < 8; ++c)
#pragma unroll
    for (int j = 0; j < 16; ++j) v[j] += p[c * 4096 + t + j * 256];
#pragma unroll
  for (int j = 0; j < 16; ++j) {
    int q = t + j * 256;
    ssum[q >> 6][q & 63] = v[j];
  }
  __syncthreads();
  if (t < 64) {
    float mx = -1e30f;
    for (int e = 0; e < 64; ++e) mx = fmaxf(mx, ssum[t][e]);
    float s = 0.f;
    for (int e = 0; e < 64; ++e) {
      float ex = __expf((ssum[t][e] - mx) * 0.125f);
      ssum[t][e] = ex; s += ex;
    }
    float inv = 1.0f / s;
    bf16* ow = attn_w + (size_t)bh * 4096 + t * 64;
    for (int e = 0; e < 64; ++e) ow[e] = (bf16)(ssum[t][e] * inv);
  }
}

// ---------------------------------------------------------------------------
// PV: out^T[b][n][c] = (attn * v)^T, chunked over n. grid (8, 128).
// ---------------------------------------------------------------------------
__global__ __launch_bounds__(256) void attn_pv_kernel(
    const bf16* __restrict__ qkv, const bf16* __restrict__ attn_w,
    bf16* __restrict__ attn_t) {
  __shared__ __attribute__((aligned(16))) bf16 aw[64 * 72];
  __shared__ __attribute__((aligned(16))) bf16 Vs[128 * 72];  // reused as O^T staging
  int chunk = blockIdx.x, bh = blockIdx.y, b = bh >> 3, h = bh & 7;
  const bf16* vmat = qkv + ((size_t)b * QKV_M + 2 * INNER + h * 64) * NSPAT + chunk * 512;
  bf16* outt = attn_t + ((size_t)b * NSPAT + chunk * 512) * INNER + h * 64;

  int tid = threadIdx.x, lane = tid & 63, wid = tid >> 6;
  int lm = lane & 15, kqd = lane >> 4, d0 = wid * 16;

#pragma unroll
  for (int i = 0; i < 2; ++i) {
    int v = tid + i * 256;
    *(bf16x8*)&aw[(v >> 3) * 72 + (v & 7) * 8] = *(const bf16x8*)(attn_w + (size_t)bh * 4096 + v * 8);
  }
  __syncthreads();
  bf16x8 a0 = *(const bf16x8*)&aw[(d0 + lm) * 72 + kqd * 8];
  bf16x8 a1 = *(const bf16x8*)&aw[(d0 + lm) * 72 + 32 + kqd * 8];

  for (int nc = 0; nc < 512; nc += 128) {
    __syncthreads();
#pragma unroll
    for (int i = 0; i < 4; ++i) {
      int v = i * 256 + tid;
      int e = v & 63, nn = (v >> 6) * 8;
      bf16x8 d = *(const bf16x8*)(vmat + (size_t)e * NSPAT + nc + nn);
#pragma unroll
      for (int j = 0; j < 8; ++j) Vs[(nn + j) * 72 + e] = d[j];
    }
    __syncthreads();
    f32x4 o[8];
#pragma unroll
    for (int nt = 0; nt < 8; ++nt) {
      bf16x8 b0 = *(const bf16x8*)&Vs[(nt * 16 + lm) * 72 + kqd * 8];
      bf16x8 b1 = *(const bf16x8*)&Vs[(nt * 16 + lm) * 72 + 32 + kqd * 8];
      o[nt] = (f32x4){0.f, 0.f, 0.f, 0.f};
      o[nt] = __builtin_amdgcn_mfma_f32_16x16x32_bf16(a0, b0, o[nt], 0, 0, 0);
      o[nt] = __builtin_amdgcn_mfma_f32_16x16x32_bf16(a1, b1, o[nt], 0, 0, 0);
    }
    __syncthreads();
#pragma unroll
    for (int nt = 0; nt < 8; ++nt) {
      bf16x4 ov = { (bf16)o[nt][0], (bf16)o[nt][1], (bf16)o[nt][2], (bf16)o[nt][3] };
      *(bf16x4*)&Vs[(nt * 16 + lm) * 72 + d0 + kqd * 4] = ov;
    }
    __syncthreads();
#pragma unroll
    for (int i = 0; i < 4; ++i) {
      int v = i * 256 + tid;
      int n = v >> 3, dc = (v & 7) * 8;
      *(bf16x8*)(outt + (size_t)(nc + n) * INNER + dc) = *(const bf16x8*)&Vs[n * 72 + dc];
    }
  }
}

// ---------------------------------------------------------------------------
// LN stats + apply
// ---------------------------------------------------------------------------
__global__ void ln_stats_kernel(const float* __restrict__ part, float2* __restrict__ stats) {
  int b = threadIdx.x;
  if (b < 16) {
    const float invn = 1.0f / 2097152.0f;
    float mean = part[b * 2] * invn;
    float var  = part[b * 2 + 1] * invn - mean * mean;
    stats[b] = make_float2(mean, rsqrtf(var + 1e-5f));
  }
}

__global__ __launch_bounds__(256) void ln_apply_kernel(
    float* __restrict__ out, const float2* __restrict__ stats,
    const float* __restrict__ gamma, const float* __restrict__ beta) {
  size_t i4 = (size_t)blockIdx.x * 256 + threadIdx.x;
  size_t e  = i4 * 4;
  int b = (int)(e >> 21);
  int c = (int)((e >> 12) & 511);
  float2 st = stats[b];
  float g  = gamma[c] * st.y;
  float bb = beta[c] - st.x * g;
  float4* p = (float4*)out;
  float4 v = p[i4];
  v.x = v.x * g + bb; v.y = v.y * g + bb; v.z = v.z * g + bb; v.w = v.w * g + bb;
  p[i4] = v;
}

// ---------------------------------------------------------------------------
extern "C" void kernel_launch(void* const* d_in, const int* in_sizes, int n_in,
                              void* d_out, int out_size, void* d_ws, size_t ws_size,
                              hipStream_t stream) {
  const float* x      = (const float*)d_in[0];
  const float* w_qkv  = (const float*)d_in[1];
  const float* w_out  = (const float*)d_in[2];
  const float* b_out  = (const float*)d_in[3];
  const float* gamma  = (const float*)d_in[4];
  const float* beta   = (const float*)d_in[5];
  float* out = (float*)d_out;

  char* ws = (char*)d_ws;
  bf16*   xt      = (bf16*)(ws);                    // 64 MiB (B, N, C) — freed after QKV gemm
  float*  sc_part = (float*)(ws);                   // 16 MiB overlay (after xt's last use)
  bf16*   attn_w  = (bf16*)(ws + 16777216);         //  1 MiB overlay
  bf16*   wqkvb   = (bf16*)(ws + 67108864);         // 1.5 MiB
  bf16*   woutb   = (bf16*)(ws + 68681728);         // 0.5 MiB
  bf16*   qkvb    = (bf16*)(ws + 69206016);         // 192 MiB (B, 1536, N)
  bf16*   attn_t  = (bf16*)(ws + 270532608);        //  64 MiB (B, N, C)
  float*  part    = (float*)(ws + 337641472);       // 32 f32
  float2* stats   = (float2*)(ws + 337641600);      // 16 float2

  hipMemsetAsync(part, 0, 128, stream);

  transpose_cast_kernel<<<dim3(64, 8, BATCH), 256, 0, stream>>>(x, xt);
  cast_f32_bf16_kernel<<<768, 256, 0, stream>>>(w_qkv, wqkvb, 196608);
  cast_f32_bf16_kernel<<<256, 256, 0, stream>>>(w_out, woutb, 65536);

  // QKV projection: (1536x512) x (512x4096)^T per batch -> qkvb bf16 (256^2 pipelined)
  gemm256_kernel<0><<<dim3(16, 6, BATCH), 512, 0, stream>>>(
      wqkvb, xt, (void*)qkvb, nullptr, nullptr, QKV_M, NSPAT);

  // channel attention
  attn_scores_kernel<<<dim3(8, 128), 256, 0, stream>>>(qkvb, sc_part);
  attn_softmax_kernel<<<128, 256, 0, stream>>>(sc_part, attn_w);
  attn_pv_kernel<<<dim3(8, 128), 256, 0, stream>>>(qkvb, attn_w, attn_t);

  // output projection + bias + LN partials -> d_out f32 (128^2 latency-tolerant)
  gemm_tn_kernel<1><<<dim3(32, 4, BATCH), 256, 0, stream>>>(
      woutb, attn_t, (void*)out, b_out, part, INNER, NSPAT, CDIM);

  ln_stats_kernel<<<1, 16, 0, stream>>>(part, stats);
  ln_apply_kernel<<<32768, 256, 0, stream>>>(out, stats, gamma, beta);
}

// Round 4
// 546.303 us; speedup vs baseline: 1.0879x; 1.0298x over previous
//
#include <hip/hip_runtime.h>

typedef __bf16 bf16;
typedef __bf16 bf16x8 __attribute__((ext_vector_type(8)));
typedef __bf16 bf16x4 __attribute__((ext_vector_type(4)));
typedef float  f32x4  __attribute__((ext_vector_type(4)));

#define BATCH   16
#define CDIM    512
#define NSPAT   4096
#define QKV_M   1536
#define INNER   512
#define GK      512   // K for both GEMMs

// async global->LDS, 16B per lane; LDS dest = wave-uniform base + lane*16
__device__ __forceinline__ void gld16(const bf16* g, const bf16* l) {
  __builtin_amdgcn_global_load_lds(
      (const __attribute__((address_space(1))) void*)g,
      (__attribute__((address_space(3))) void*)l, 16, 0, 0);
}

// raw barrier with compile-time memory fences (no vmcnt drain, unlike __syncthreads)
#define SBAR() do { asm volatile("" ::: "memory"); __builtin_amdgcn_s_barrier(); \
                    asm volatile("" ::: "memory"); } while (0)
#define VMCNT(n) asm volatile("s_waitcnt vmcnt(" #n ")" ::: "memory")

// ---------------------------------------------------------------------------
// f32 -> bf16 cast (weights)
// ---------------------------------------------------------------------------
__global__ __launch_bounds__(256) void cast_f32_bf16_kernel(
    const float* __restrict__ in, bf16* __restrict__ out, int n4) {
  int i = blockIdx.x * 256 + threadIdx.x;
  if (i >= n4) return;
  float4 v = ((const float4*)in)[i];
  bf16x4 o = { (bf16)v.x, (bf16)v.y, (bf16)v.z, (bf16)v.w };
  *(bf16x4*)(out + (size_t)i * 4) = o;
}

// ---------------------------------------------------------------------------
// x (B, C=512, N=4096) f32 -> xt (B, N, C) bf16   (64x64 LDS tile transpose)
// ---------------------------------------------------------------------------
__global__ __launch_bounds__(256) void transpose_cast_kernel(
    const float* __restrict__ x, bf16* __restrict__ xt) {
  __shared__ __attribute__((aligned(16))) bf16 T[64][72];
  int b = blockIdx.z, c0 = blockIdx.y * 64, n0 = blockIdx.x * 64;
  int t = threadIdx.x;
  const float* xp = x + ((size_t)b * CDIM + c0) * NSPAT + n0;
#pragma unroll
  for (int i = 0; i < 4; ++i) {
    int v = t + i * 256;
    int c = v >> 4, nq = (v & 15) * 4;
    float4 rd = *(const float4*)(xp + (size_t)c * NSPAT + nq);
    T[nq + 0][c] = (bf16)rd.x; T[nq + 1][c] = (bf16)rd.y;
    T[nq + 2][c] = (bf16)rd.z; T[nq + 3][c] = (bf16)rd.w;
  }
  __syncthreads();
  bf16* op = xt + ((size_t)b * NSPAT + n0) * CDIM + c0;
#pragma unroll
  for (int i = 0; i < 2; ++i) {
    int v = t + i * 256;
    int n = v >> 3, cc = (v & 7) * 8;
    *(bf16x8*)(op + (size_t)n * CDIM + cc) = *(const bf16x8*)&T[n][cc];
  }
}

// ---------------------------------------------------------------------------
// GEMM, 256x256 tile / pipelined ring schedule (T2+T3+T4+T5) — used for QKV.
//   C[b] = A(M,K) * Bt[b](N,K)^T, both k-contiguous, K=512 fixed.
//   512 thr = 8 waves (2m x 4n), per-wave 128x64 out, BK=32, 16 K-tiles.
//   LDS: 4-deep K-tile ring, 32 KiB/tile (A 16K ++ B 16K) = 128 KiB.
//   Swizzle f(x)=x^((x>>3)&7) on 16B slots (both-sides). vmcnt counted,
//   never drained in-loop.
//   r3/r4: ONE barrier per K-tile. All 12 ds_reads + both stages issued up
//   front; compiler inserts counted lgkmcnt before the two MFMA clusters,
//   so reads+stage-issue overlap MFMA drain. Hazards:
//   WAR: stage(t+3) hits slot (t-1)&3; every wave's slot-(t-1) reads
//   completed (in-order lgkm, waited before its cluster-2) before its
//   end-of-(t-1) barrier. RAW: VMCNT(8) leaves exactly tiles t+2,t+3
//   outstanding at each closing barrier -> tile t+1's data landed.
//   Requires a cache-settled B operand (xt); do NOT use for out-proj
//   (freshly-dirty attn_t stalls the 2-wave/SIMD schedule — r1 evidence).
// ---------------------------------------------------------------------------
template <int OUTMODE>
__global__ __launch_bounds__(512, 2) void gemm256_kernel(
    const bf16* __restrict__ A, const bf16* __restrict__ Bt,
    void* __restrict__ Cout, const float* __restrict__ bias,
    float* __restrict__ part, int M, int N) {
  __shared__ __attribute__((aligned(16))) bf16 Sm[65536];  // 128 KiB

  int bz = blockIdx.z;
  int m0 = blockIdx.y * 256, n0 = blockIdx.x * 256;
  int tid = threadIdx.x, lane = tid & 63, wid = tid >> 6;
  int wm = wid >> 2, wn = wid & 3;          // 2 x 4 wave grid
  int lm = lane & 15, kqd = lane >> 4;

  // swizzled ds_read element-offsets (A-frags mf=0..7, B-frags nf=0..3)
  int aoff[8], boff[4];
#pragma unroll
  for (int mf = 0; mf < 8; ++mf) {
    int x = (mf * 16 + lm) * 4 + kqd;
    aoff[mf] = wm * 4096 + (x ^ ((x >> 3) & 7)) * 8;
  }
#pragma unroll
  for (int nf = 0; nf < 4; ++nf) {
    int x = ((wn & 1) * 64 + nf * 16 + lm) * 4 + kqd;
    boff[nf] = 8192 + (wn >> 1) * 4096 + (x ^ ((x >> 3) & 7)) * 8;
  }

  // staging: thread tid fills 16B slot #tid of each 128x32 half; pre-swizzled source
  int sl = tid ^ ((tid >> 3) & 7);
  int srow = sl >> 2, sc8 = (sl & 3) * 8;
  const bf16* aS = A + (size_t)(m0 + srow) * GK + sc8;
  const bf16* bS = Bt + ((size_t)bz * N + n0 + srow) * GK + sc8;

  f32x4 acc[8][4] = {};

#define STG_A(t) do { bf16* d = Sm + (((t)) & 3) * 16384 + wid * 512; \
    gld16(aS + (size_t)(t) * 32, d); \
    gld16(aS + (size_t)128 * GK + (size_t)(t) * 32, d + 4096); } while (0)
#define STG_B(t) do { bf16* d = Sm + (((t)) & 3) * 16384 + 8192 + wid * 512; \
    gld16(bS + (size_t)(t) * 32, d); \
    gld16(bS + (size_t)128 * GK + (size_t)(t) * 32, d + 4096); } while (0)

  // prologue: tiles 0,1,2 in flight; wait tile 0 (oldest 4 of 12 loads)
  STG_A(0); STG_B(0); STG_A(1); STG_B(1); STG_A(2); STG_B(2);
  VMCNT(8);
  SBAR();

  // one barrier per K-tile; reads+stage issue overlap MFMA via counted lgkm
#define TILE_BODY(t, DOSTG, WAITK) do { \
    const bf16* Sb = Sm + ((t) & 3) * 16384; \
    bf16x8 af[8], bq[4]; \
    _Pragma("unroll") for (int i = 0; i < 4; ++i) af[i] = *(const bf16x8*)(Sb + aoff[i]); \
    _Pragma("unroll") for (int i = 0; i < 4; ++i) bq[i] = *(const bf16x8*)(Sb + boff[i]); \
    _Pragma("unroll") for (int i = 0; i < 4; ++i) af[4 + i] = *(const bf16x8*)(Sb + aoff[4 + i]); \
    if (DOSTG) { STG_A((t) + 3); STG_B((t) + 3); } \
    __builtin_amdgcn_s_setprio(1); \
    _Pragma("unroll") for (int i = 0; i < 4; ++i) \
      _Pragma("unroll") for (int j = 0; j < 4; ++j) \
        acc[i][j] = __builtin_amdgcn_mfma_f32_16x16x32_bf16(af[i], bq[j], acc[i][j], 0, 0, 0); \
    _Pragma("unroll") for (int i = 0; i < 4; ++i) \
      _Pragma("unroll") for (int j = 0; j < 4; ++j) \
        acc[4 + i][j] = __builtin_amdgcn_mfma_f32_16x16x32_bf16(af[4 + i], bq[j], acc[4 + i][j], 0, 0, 0); \
    __builtin_amdgcn_s_setprio(0); \
    WAITK; \
    SBAR(); \
  } while (0)

  for (int tt = 0; tt < 12; tt += 4) {
#pragma unroll
    for (int q = 0; q < 4; ++q) TILE_BODY(tt + q, 1, VMCNT(8));
  }
  TILE_BODY(12, 1, VMCNT(8));   // stages tile 15
  TILE_BODY(13, 0, VMCNT(4));   // tile 14 landed, 15 in flight
  TILE_BODY(14, 0, VMCNT(0));   // tile 15 landed
  TILE_BODY(15, 0, (void)0);

  // C/D layout: col = n-base + lane&15, row = m-base + (lane>>4)*4 + r
  if (OUTMODE == 0) {
    bf16* C = (bf16*)Cout + (size_t)bz * M * N;
    bf16* Ws = Sm + wid * 8192;   // per-wave 128x64 staging (disjoint, no barriers)
#pragma unroll
    for (int mf = 0; mf < 8; ++mf)
#pragma unroll
      for (int nf = 0; nf < 4; ++nf)
#pragma unroll
        for (int r = 0; r < 4; ++r)
          Ws[(mf * 16 + kqd * 4 + r) * 64 + nf * 16 + lm] = (bf16)acc[mf][nf][r];
#pragma unroll
    for (int j = 0; j < 16; ++j) {
      int u = j * 64 + lane;
      int row = u >> 3, cu = (u & 7) * 8;
      *(bf16x8*)(C + (size_t)(m0 + wm * 128 + row) * N + (n0 + wn * 64 + cu)) =
          *(const bf16x8*)&Ws[row * 64 + cu];
    }
  } else {
    float* C = (float*)Cout + (size_t)bz * M * N;
    float s = 0.f, s2 = 0.f;
#pragma unroll
    for (int mf = 0; mf < 8; ++mf)
#pragma unroll
      for (int nf = 0; nf < 4; ++nf) {
        int row = m0 + wm * 128 + mf * 16 + kqd * 4;
        int col = n0 + wn * 64 + nf * 16 + lm;
#pragma unroll
        for (int r = 0; r < 4; ++r) {
          float v = acc[mf][nf][r] + bias[row + r];
          C[(size_t)(row + r) * N + col] = v;
          s += v; s2 += v * v;
        }
      }
#pragma unroll
    for (int off = 32; off > 0; off >>= 1) {
      s  += __shfl_down(s, off, 64);
      s2 += __shfl_down(s2, off, 64);
    }
    if (lane == 0) {
      atomicAdd(&part[bz * 2],     s);
      atomicAdd(&part[bz * 2 + 1], s2);
    }
  }
#undef TILE_BODY
#undef STG_A
#undef STG_B
}

// ---------------------------------------------------------------------------
// GEMM (m97 structure, known-good): used for the out-projection.
// 128x128 tile, BK=32, global_load_lds staging, 4 waves x (4x4) 16x16x32 MFMA.
// __syncthreads-drain schedule, 16 KiB LDS -> ~3 blocks/CU: latency-tolerant
// to the freshly-dirty attn_t B-operand (the 256^2 ring kernel is not).
// ---------------------------------------------------------------------------
template <int OUTMODE>
__global__ __launch_bounds__(256) void gemm_tn_kernel(
    const bf16* __restrict__ A, const bf16* __restrict__ Bt,
    void* __restrict__ Cout, const float* __restrict__ bias,
    float* __restrict__ part, int M, int N, int K) {
  __shared__ __attribute__((aligned(16))) bf16 smem[8192];  // As[4096] ++ Bs[4096]

  int b  = blockIdx.z;
  int m0 = blockIdx.y * 128, n0 = blockIdx.x * 128;
  const bf16* Ab = A + (size_t)m0 * K;
  const bf16* Bb = Bt + ((size_t)b * N + n0) * K;

  int tid = threadIdx.x, lane = tid & 63, wid = tid >> 6;
  int wm = wid >> 1, wn = wid & 1, lm = lane & 15, kqd = lane >> 4;
  int srow = lane >> 2, skb = lane & 3;

  f32x4 acc[4][4] = {};

  for (int k0 = 0; k0 < K; k0 += 32) {
#pragma unroll
    for (int i = 0; i < 2; ++i) {
      int gi = wid * 2 + i;
      gld16(Ab + (size_t)(gi * 16 + srow) * K + k0 + skb * 8, smem + gi * 512);
      gld16(Bb + (size_t)(gi * 16 + srow) * K + k0 + skb * 8, smem + 4096 + gi * 512);
    }
    __syncthreads();
    bf16x8 af[4], bfr[4];
#pragma unroll
    for (int im = 0; im < 4; ++im)
      af[im] = *(const bf16x8*)&smem[(wm * 64 + im * 16 + lm) * 32 + kqd * 8];
#pragma unroll
    for (int in = 0; in < 4; ++in)
      bfr[in] = *(const bf16x8*)&smem[4096 + (wn * 64 + in * 16 + lm) * 32 + kqd * 8];
#pragma unroll
    for (int im = 0; im < 4; ++im)
#pragma unroll
      for (int in = 0; in < 4; ++in)
        acc[im][in] = __builtin_amdgcn_mfma_f32_16x16x32_bf16(af[im], bfr[in], acc[im][in], 0, 0, 0);
    __syncthreads();
  }

  // C/D layout: col = lane&15, row = (lane>>4)*4 + r
  if (OUTMODE == 0) {
    bf16* C = (bf16*)Cout + (size_t)b * M * N;
    bf16* Ws = smem + wid * 2048;   // per-wave 32x64 staging (no barriers needed)
#pragma unroll
    for (int half = 0; half < 2; ++half) {
#pragma unroll
      for (int im2 = 0; im2 < 2; ++im2) {
        int im = half * 2 + im2;
#pragma unroll
        for (int in = 0; in < 4; ++in)
#pragma unroll
          for (int r = 0; r < 4; ++r)
            Ws[(im2 * 16 + kqd * 4 + r) * 64 + in * 16 + lm] = (bf16)acc[im][in][r];
      }
#pragma unroll
      for (int j = 0; j < 4; ++j) {
        int u = lane + j * 64;
        int row = u >> 3, cu = (u & 7) * 8;
        *(bf16x8*)(C + (size_t)(m0 + wm * 64 + half * 32 + row) * N + n0 + wn * 64 + cu) =
            *(const bf16x8*)&Ws[row * 64 + cu];
      }
    }
  } else {
    float* C = (float*)Cout + (size_t)b * M * N;
    float s = 0.f, s2 = 0.f;
#pragma unroll
    for (int im = 0; im < 4; ++im)
#pragma unroll
      for (int in = 0; in < 4; ++in) {
        int row = m0 + wm * 64 + im * 16 + kqd * 4;
        int col = n0 + wn * 64 + in * 16 + lm;
#pragma unroll
        for (int r = 0; r < 4; ++r) {
          float v = acc[im][in][r] + bias[row + r];
          C[(size_t)(row + r) * N + col] = v;
          s += v; s2 += v * v;
        }
      }
#pragma unroll
    for (int off = 32; off > 0; off >>= 1) {
      s  += __shfl_down(s, off, 64);
      s2 += __shfl_down(s2, off, 64);
    }
    __shared__ float red[8];
    if (lane == 0) { red[wid] = s; red[wid + 4] = s2; }
    __syncthreads();
    if (tid == 0) {
      atomicAdd(&part[b * 2],     red[0] + red[1] + red[2] + red[3]);
      atomicAdd(&part[b * 2 + 1], red[4] + red[5] + red[6] + red[7]);
    }
  }
}

// ---------------------------------------------------------------------------
// Attention scores, chunked: partial sc[bh][chunk][d][e] = sum_{n in chunk} q*k
// ---------------------------------------------------------------------------
__global__ __launch_bounds__(256) void attn_scores_kernel(
    const bf16* __restrict__ qkv, float* __restrict__ sc_part) {
  __shared__ __attribute__((aligned(16))) bf16 qs[4096];  // Qs[2048] ++ Ks[2048]
  int chunk = blockIdx.x, bh = blockIdx.y, b = bh >> 3, h = bh & 7;
  const bf16* q = qkv + ((size_t)b * QKV_M + h * 64) * NSPAT + chunk * 512;
  const bf16* k = q + (size_t)INNER * NSPAT;

  int tid = threadIdx.x, lane = tid & 63, wid = tid >> 6;
  int lm = lane & 15, kqd = lane >> 4, d0 = wid * 16;
  int srow = lane >> 2, skb = lane & 3;

  f32x4 acc[4] = {};
  for (int n0 = 0; n0 < 512; n0 += 32) {
    gld16(q + (size_t)(wid * 16 + srow) * NSPAT + n0 + skb * 8, qs + wid * 512);
    gld16(k + (size_t)(wid * 16 + srow) * NSPAT + n0 + skb * 8, qs + 2048 + wid * 512);
    __syncthreads();
    bf16x8 a = *(const bf16x8*)&qs[(d0 + lm) * 32 + kqd * 8];
#pragma unroll
    for (int eb = 0; eb < 4; ++eb) {
      bf16x8 bb = *(const bf16x8*)&qs[2048 + (eb * 16 + lm) * 32 + kqd * 8];
      acc[eb] = __builtin_amdgcn_mfma_f32_16x16x32_bf16(a, bb, acc[eb], 0, 0, 0);
    }
    __syncthreads();
  }
  float* outp = sc_part + ((size_t)bh * 8 + chunk) * 4096;
#pragma unroll
  for (int eb = 0; eb < 4; ++eb)
#pragma unroll
    for (int r = 0; r < 4; ++r)
      outp[(d0 + kqd * 4 + r) * 64 + eb * 16 + lm] = acc[eb][r];
}

// ---------------------------------------------------------------------------
// Softmax: sum 8 partial chunks, scale 1/8, softmax rows, bf16 attn weights
// ---------------------------------------------------------------------------
__global__ __launch_bounds__(256) void attn_softmax_kernel(
    const float* __restrict__ sc_part, bf16* __restrict__ attn_w) {
  __shared__ float ssum[64][65];
  int bh = blockIdx.x, t = threadIdx.x;
  const float* p = sc_part + (size_t)bh * 8 * 4096;
  float v[16];
#pragma unroll
  for (int j = 0; j < 16; ++j) v[j] = p[t + j * 256];
  for (int c = 1; c < 8; ++c)
#pragma unroll
    for (int j = 0; j < 16; ++j) v[j] += p[c * 4096 + t + j * 256];
#pragma unroll
  for (int j = 0; j < 16; ++j) {
    int q = t + j * 256;
    ssum[q >> 6][q & 63] = v[j];
  }
  __syncthreads();
  if (t < 64) {
    float mx = -1e30f;
    for (int e = 0; e < 64; ++e) mx = fmaxf(mx, ssum[t][e]);
    float s = 0.f;
    for (int e = 0; e < 64; ++e) {
      float ex = __expf((ssum[t][e] - mx) * 0.125f);
      ssum[t][e] = ex; s += ex;
    }
    float inv = 1.0f / s;
    bf16* ow = attn_w + (size_t)bh * 4096 + t * 64;
    for (int e = 0; e < 64; ++e) ow[e] = (bf16)(ssum[t][e] * inv);
  }
}

// ---------------------------------------------------------------------------
// PV: out^T[b][n][c] = (attn * v)^T, chunked over n. grid (8, 128).
// ---------------------------------------------------------------------------
__global__ __launch_bounds__(256) void attn_pv_kernel(
    const bf16* __restrict__ qkv, const bf16* __restrict__ attn_w,
    bf16* __restrict__ attn_t) {
  __shared__ __attribute__((aligned(16))) bf16 aw[64 * 72];
  __shared__ __attribute__((aligned(16))) bf16 Vs[128 * 72];  // reused as O^T staging
  int chunk = blockIdx.x, bh = blockIdx.y, b = bh >> 3, h = bh & 7;
  const bf16* vmat = qkv + ((size_t)b * QKV_M + 2 * INNER + h * 64) * NSPAT + chunk * 512;
  bf16* outt = attn_t + ((size_t)b * NSPAT + chunk * 512) * INNER + h * 64;

  int tid = threadIdx.x, lane = tid & 63, wid = tid >> 6;
  int lm = lane & 15, kqd = lane >> 4, d0 = wid * 16;

#pragma unroll
  for (int i = 0; i < 2; ++i) {
    int v = tid + i * 256;
    *(bf16x8*)&aw[(v >> 3) * 72 + (v & 7) * 8] = *(const bf16x8*)(attn_w + (size_t)bh * 4096 + v * 8);
  }
  __syncthreads();
  bf16x8 a0 = *(const bf16x8*)&aw[(d0 + lm) * 72 + kqd * 8];
  bf16x8 a1 = *(const bf16x8*)&aw[(d0 + lm) * 72 + 32 + kqd * 8];

  for (int nc = 0; nc < 512; nc += 128) {
    __syncthreads();
#pragma unroll
    for (int i = 0; i < 4; ++i) {
      int v = i * 256 + tid;
      int e = v & 63, nn = (v >> 6) * 8;
      bf16x8 d = *(const bf16x8*)(vmat + (size_t)e * NSPAT + nc + nn);
#pragma unroll
      for (int j = 0; j < 8; ++j) Vs[(nn + j) * 72 + e] = d[j];
    }
    __syncthreads();
    f32x4 o[8];
#pragma unroll
    for (int nt = 0; nt < 8; ++nt) {
      bf16x8 b0 = *(const bf16x8*)&Vs[(nt * 16 + lm) * 72 + kqd * 8];
      bf16x8 b1 = *(const bf16x8*)&Vs[(nt * 16 + lm) * 72 + 32 + kqd * 8];
      o[nt] = (f32x4){0.f, 0.f, 0.f, 0.f};
      o[nt] = __builtin_amdgcn_mfma_f32_16x16x32_bf16(a0, b0, o[nt], 0, 0, 0);
      o[nt] = __builtin_amdgcn_mfma_f32_16x16x32_bf16(a1, b1, o[nt], 0, 0, 0);
    }
    __syncthreads();
#pragma unroll
    for (int nt = 0; nt < 8; ++nt) {
      bf16x4 ov = { (bf16)o[nt][0], (bf16)o[nt][1], (bf16)o[nt][2], (bf16)o[nt][3] };
      *(bf16x4*)&Vs[(nt * 16 + lm) * 72 + d0 + kqd * 4] = ov;
    }
    __syncthreads();
#pragma unroll
    for (int i = 0; i < 4; ++i) {
      int v = i * 256 + tid;
      int n = v >> 3, dc = (v & 7) * 8;
      *(bf16x8*)(outt + (size_t)(nc + n) * INNER + dc) = *(const bf16x8*)&Vs[n * 72 + dc];
    }
  }
}

// ---------------------------------------------------------------------------
// LN stats + apply
// ---------------------------------------------------------------------------
__global__ void ln_stats_kernel(const float* __restrict__ part, float2* __restrict__ stats) {
  int b = threadIdx.x;
  if (b < 16) {
    const float invn = 1.0f / 2097152.0f;
    float mean = part[b * 2] * invn;
    float var  = part[b * 2 + 1] * invn - mean * mean;
    stats[b] = make_float2(mean, rsqrtf(var + 1e-5f));
  }
}

__global__ __launch_bounds__(256) void ln_apply_kernel(
    float* __restrict__ out, const float2* __restrict__ stats,
    const float* __restrict__ gamma, const float* __restrict__ beta) {
  size_t i4 = (size_t)blockIdx.x * 256 + threadIdx.x;
  size_t e  = i4 * 4;
  int b = (int)(e >> 21);
  int c = (int)((e >> 12) & 511);
  float2 st = stats[b];
  float g  = gamma[c] * st.y;
  float bb = beta[c] - st.x * g;
  float4* p = (float4*)out;
  float4 v = p[i4];
  v.x = v.x * g + bb; v.y = v.y * g + bb; v.z = v.z * g + bb; v.w = v.w * g + bb;
  p[i4] = v;
}

// ---------------------------------------------------------------------------
extern "C" void kernel_launch(void* const* d_in, const int* in_sizes, int n_in,
                              void* d_out, int out_size, void* d_ws, size_t ws_size,
                              hipStream_t stream) {
  const float* x      = (const float*)d_in[0];
  const float* w_qkv  = (const float*)d_in[1];
  const float* w_out  = (const float*)d_in[2];
  const float* b_out  = (const float*)d_in[3];
  const float* gamma  = (const float*)d_in[4];
  const float* beta   = (const float*)d_in[5];
  float* out = (float*)d_out;

  char* ws = (char*)d_ws;
  bf16*   xt      = (bf16*)(ws);                    // 64 MiB (B, N, C) — freed after QKV gemm
  float*  sc_part = (float*)(ws);                   // 16 MiB overlay (after xt's last use)
  bf16*   attn_w  = (bf16*)(ws + 16777216);         //  1 MiB overlay
  bf16*   wqkvb   = (bf16*)(ws + 67108864);         // 1.5 MiB
  bf16*   woutb   = (bf16*)(ws + 68681728);         // 0.5 MiB
  bf16*   qkvb    = (bf16*)(ws + 69206016);         // 192 MiB (B, 1536, N)
  bf16*   attn_t  = (bf16*)(ws + 270532608);        //  64 MiB (B, N, C)
  float*  part    = (float*)(ws + 337641472);       // 32 f32
  float2* stats   = (float2*)(ws + 337641600);      // 16 float2

  hipMemsetAsync(part, 0, 128, stream);

  transpose_cast_kernel<<<dim3(64, 8, BATCH), 256, 0, stream>>>(x, xt);
  cast_f32_bf16_kernel<<<768, 256, 0, stream>>>(w_qkv, wqkvb, 196608);
  cast_f32_bf16_kernel<<<256, 256, 0, stream>>>(w_out, woutb, 65536);

  // QKV projection: (1536x512) x (512x4096)^T per batch -> qkvb bf16 (256^2 pipelined)
  gemm256_kernel<0><<<dim3(16, 6, BATCH), 512, 0, stream>>>(
      wqkvb, xt, (void*)qkvb, nullptr, nullptr, QKV_M, NSPAT);

  // channel attention
  attn_scores_kernel<<<dim3(8, 128), 256, 0, stream>>>(qkvb, sc_part);
  attn_softmax_kernel<<<128, 256, 0, stream>>>(sc_part, attn_w);
  attn_pv_kernel<<<dim3(8, 128), 256, 0, stream>>>(qkvb, attn_w, attn_t);

  // output projection + bias + LN partials -> d_out f32 (128^2 latency-tolerant)
  gemm_tn_kernel<1><<<dim3(32, 4, BATCH), 256, 0, stream>>>(
      woutb, attn_t, (void*)out, b_out, part, INNER, NSPAT, CDIM);

  ln_stats_kernel<<<1, 16, 0, stream>>>(part, stats);
  ln_apply_kernel<<<32768, 256, 0, stream>>>(out, stats, gamma, beta);
}